// Round 19
// baseline (18.897 us; speedup 1.0000x reference)
//
#include <hip/hip_runtime.h>
#include <hip/hip_fp16.h>

// CropRoi: 3D adaptive max-pool over per-proposal crop boxes.
// f:        [B=4, C=64, 24, 24, 24] f32
// proposals:[N, 8] f32 = [b, score, cx, cy, cz, sx, sy, sz]
// out:      [N, C, 7, 7, 7] f32
//
// r18 = r17 with the compile fix: __builtin_nontemporal_load needs a native
// clang vector type (ext_vector_type), not HIP_vector_type float4.
// K1: 3456 blocks (16-spatial x 64-ch tile): 1 NT vfloat4 load + <=1 uint4
//     store per thread (minimal serial chain).
// K2: r15's j-split streaming pool verbatim + NT scalar stores of out.
//
// Plateau ledger: traffic cut (r16) null; wave-halving (r11) null; block
// count (r8/r11) null; predication (r8) -3.1us; occupancy splits (r15)
// -1.3us. K2 is latency/ramp-governed, not BW/issue-bound.
// History: r9 grid.sync / r12 pc-flag 100-155us — intra-dispatch cross-XCD
// sync is dead on MI355X. r13 direct-f32 52.8us — serial LDS chains dead.
// Precision: fp16 RTN on ~N(0,1); absmax 0.03125 << 0.099.

#define SS 7
#define CC 64
#define DP 24
#define DP2 (DP*DP)        // 576
#define VOL (DP*DP*DP)     // 13824
#define INV_SCALE 0.25f
#define NEGINF2 0xFC00FC00u

typedef float vfloat4 __attribute__((ext_vector_type(4)));

static __device__ __forceinline__ unsigned pkmax(unsigned a, unsigned b) {
    unsigned r;
    asm("v_pk_max_f16 %0, %1, %2" : "=v"(r) : "v"(a), "v"(b));
    return r;
}
static __device__ __forceinline__ uint4 pkmax4(uint4 a, uint4 b) {
    uint4 r;
    r.x = pkmax(a.x, b.x); r.y = pkmax(a.y, b.y);
    r.z = pkmax(a.z, b.z); r.w = pkmax(a.w, b.w);
    return r;
}

// ---------------- kernel 1: channel-last transpose to fp16 ----------------
// 16-spatial x 64-channel tile; 3456 blocks; 1 NT vfloat4 load / thread.
__global__ __launch_bounds__(256) void transpose_cl(
    const float* __restrict__ f,   // [B][CC][VOL] f32
    uint4* __restrict__ ft4)       // [B][VOL][CC/8]
{
    __shared__ float tile[64][17];     // 4352 B
    const int b  = blockIdx.y;
    const int s0 = blockIdx.x * 16;
    const int t  = threadIdx.x;

    // load: thread t -> channel r = t>>2, spatial quad x4 = (t&3)*4
    {
        const int r  = t >> 2;
        const int x4 = (t & 3) * 4;
        const vfloat4 v = __builtin_nontemporal_load(
            (const vfloat4*)&f[(size_t)(b * CC + r) * VOL + s0 + x4]);
        tile[r][x4 + 0] = v.x; tile[r][x4 + 1] = v.y;
        tile[r][x4 + 2] = v.z; tile[r][x4 + 3] = v.w;
    }
    __syncthreads();

    // store: threads 0..127: s = t>>3, c8 = (t&7)*8; 8 lanes = 128B point
    if (t < 128) {
        const int s  = t >> 3;
        const int c8 = (t & 7) * 8;
        __half h[8];
        #pragma unroll
        for (int u = 0; u < 8; ++u)
            h[u] = __float2half(tile[c8 + u][s]);
        ft4[((size_t)b * VOL + s0 + s) * (CC / 8) + (c8 >> 3)] = *(uint4*)h;
    }
}

// ---------------- kernel 2: streaming separable pool, j-split (r15) --------
__global__ __launch_bounds__(256) void croproi_stream(
    const __half* __restrict__ ft,    // [B][VOL][CC] fp16
    const float* __restrict__ props,  // [N][8]
    float* __restrict__ out)          // [N][CC][343] f32
{
    __shared__ uint4 P[4 * 104];      // [j_local][x(13)][c8(8)]  6656 B
    __shared__ float obuf[28 * 68];   // 7616 B
    const int n  = blockIdx.x;
    const int i  = blockIdx.y;        // z-bin slice
    const int zc = blockIdx.z;        // j-half: 0 -> j 0..3, 1 -> j 4..6
    const int t  = threadIdx.x;

    // ---- box decode (wave-uniform -> SGPR) ----
    const float* p = props + (size_t)n * 8;
    int b = (int)p[0];
    int lo0, lo1, lo2, L0, L1, L2;
    {
        float c0f = p[2] - 0.5f * p[5];
        float c1f = c0f + p[5];
        int lo = (int)floorf(c0f * INV_SCALE); if (lo < 0) lo = 0;
        int hi = (int)ceilf (c1f * INV_SCALE); if (hi > DP) hi = DP;
        lo0 = lo; L0 = hi - lo;

        c0f = p[3] - 0.5f * p[6];
        c1f = c0f + p[6];
        lo = (int)floorf(c0f * INV_SCALE); if (lo < 0) lo = 0;
        hi = (int)ceilf (c1f * INV_SCALE); if (hi > DP) hi = DP;
        lo1 = lo; L1 = hi - lo;

        c0f = p[4] - 0.5f * p[7];
        c1f = c0f + p[7];
        lo = (int)floorf(c0f * INV_SCALE); if (lo < 0) lo = 0;
        hi = (int)ceilf (c1f * INV_SCALE); if (hi > DP) hi = DP;
        lo2 = lo; L2 = hi - lo;
    }
    b   = __builtin_amdgcn_readfirstlane(b);
    lo0 = __builtin_amdgcn_readfirstlane(lo0);
    lo1 = __builtin_amdgcn_readfirstlane(lo1);
    lo2 = __builtin_amdgcn_readfirstlane(lo2);
    L0  = __builtin_amdgcn_readfirstlane(L0);
    L1  = __builtin_amdgcn_readfirstlane(L1);
    L2  = __builtin_amdgcn_readfirstlane(L2);

    const int zs = (i * L0) / SS;
    const int ez = ((i + 1) * L0 + 6) / SS - zs;        // 1..3 (uniform)
    const int jlo = zc ? 4 : 0;
    const int nj  = zc ? 3 : 4;

    // base at (b, lo0+zs, lo1, lo2), channel 0, in uint4 units (8/point)
    const uint4* base0 = (const uint4*)ft
        + ((size_t)b * VOL + (size_t)(lo0 + zs) * DP2
           + (size_t)lo1 * DP + lo2) * 8;

    // ---- phase A: zy-pool streaming loads -> P[j_local][x][c8] ----
    const int unitsA = nj * 104;
    for (int u = t; u < unitsA; u += 256) {
        const int jl = u / 104;                 // const-divisor magic
        const int r  = u - jl * 104;
        const int x  = r >> 3;
        const int c8 = r & 7;
        const int j  = jlo + jl;
        const int ys = (j * L1) / SS;
        const int ey = ((j + 1) * L1 + 6) / SS - ys;     // 1..3
        const bool act = (x < L2);

        const uint4* bp = base0 + (ys * DP + x) * 8 + c8;
        uint4 m; m.x = m.y = m.z = m.w = NEGINF2;
        #pragma unroll
        for (int zi = 0; zi < 3; ++zi) {
            if (zi < ez) {                      // wave-uniform branch
                const uint4* bz = bp + zi * (DP2 * 8);
                uint4 v0, v1, v2;
                v0.x = v0.y = v0.z = v0.w = NEGINF2; v1 = v0; v2 = v0;
                if (act)           v0 = bz[0];           // exec-masked
                if (act && ey > 1) v1 = bz[DP * 8];
                if (act && ey > 2) v2 = bz[2 * DP * 8];
                m = pkmax4(m, pkmax4(pkmax4(v0, v1), v2));
            }
        }
        if (act) P[jl * 104 + x * 8 + c8] = m;
    }
    __syncthreads();

    // ---- phase B: x-pool from P -> obuf f32 ----
    const int unitsB = nj * 56;                 // (nj*7 bins) * 8 c8
    if (t < unitsB) {
        const int jkl = t >> 3;                 // local bin (j_local*7 + k)
        const int c8  = t & 7;
        const int jl  = jkl / SS;               // const-divisor magic
        const int k   = jkl - jl * SS;
        const int xs  = (k * L2) / SS;
        const int ex  = ((k + 1) * L2 + 6) / SS - xs;    // 1..3
        const uint4* pp = &P[jl * 104 + xs * 8 + c8];
        uint4 m = pp[0];
        if (ex > 1) m = pkmax4(m, pp[8]);
        if (ex > 2) m = pkmax4(m, pp[16]);

        float* o = &obuf[jkl * 68 + c8 * 8];
        __half2 h;
        h = *(const __half2*)&m.x; o[0] = __half2float(h.x); o[1] = __half2float(h.y);
        h = *(const __half2*)&m.y; o[2] = __half2float(h.x); o[3] = __half2float(h.y);
        h = *(const __half2*)&m.z; o[4] = __half2float(h.x); o[5] = __half2float(h.y);
        h = *(const __half2*)&m.w; o[6] = __half2float(h.x); o[7] = __half2float(h.y);
    }
    __syncthreads();

    // ---- phase C: coalesced NT write-out (28/21-float runs per channel) ----
    float* op = out + (size_t)n * CC * (SS * SS * SS) + (size_t)i * 49 + jlo * SS;
    if (zc == 0) {
        for (int idx = t; idx < 28 * CC; idx += 256) {
            const int c = idx / 28;             // const-divisor magic
            const int q = idx - c * 28;
            __builtin_nontemporal_store(obuf[q * 68 + c],
                                        &op[(size_t)c * 343 + q]);
        }
    } else {
        for (int idx = t; idx < 21 * CC; idx += 256) {
            const int c = idx / 21;             // const-divisor magic
            const int q = idx - c * 21;
            __builtin_nontemporal_store(obuf[q * 68 + c],
                                        &op[(size_t)c * 343 + q]);
        }
    }
}

// ---------------- fallback: round-0 thread-per-bin (proven) --------
__global__ __launch_bounds__(256) void croproi_fallback(
    const float* __restrict__ f, const float* __restrict__ props,
    float* __restrict__ out, int total)
{
    int tid = blockIdx.x * blockDim.x + threadIdx.x;
    if (tid >= total) return;
    int k = tid % SS;
    int t = tid / SS;
    int j = t % SS; t /= SS;
    int i = t % SS; t /= SS;
    int c = t % CC;
    int n = t / CC;
    const float* p = props + n * 8;
    int b = (int)p[0];
    int lo0, lo1, lo2, L0, L1, L2;
    {
        float c0f = p[2] - 0.5f * p[5]; float c1f = c0f + p[5];
        int lo = (int)floorf(c0f * INV_SCALE); if (lo < 0) lo = 0;
        int hi = (int)ceilf (c1f * INV_SCALE); if (hi > DP) hi = DP;
        lo0 = lo; L0 = hi - lo;
        c0f = p[3] - 0.5f * p[6]; c1f = c0f + p[6];
        lo = (int)floorf(c0f * INV_SCALE); if (lo < 0) lo = 0;
        hi = (int)ceilf (c1f * INV_SCALE); if (hi > DP) hi = DP;
        lo1 = lo; L1 = hi - lo;
        c0f = p[4] - 0.5f * p[7]; c1f = c0f + p[7];
        lo = (int)floorf(c0f * INV_SCALE); if (lo < 0) lo = 0;
        hi = (int)ceilf (c1f * INV_SCALE); if (hi > DP) hi = DP;
        lo2 = lo; L2 = hi - lo;
    }
    int zs = lo0 + (i * L0) / SS, ze = lo0 + ((i + 1) * L0 + SS - 1) / SS;
    int ys = lo1 + (j * L1) / SS, ye = lo1 + ((j + 1) * L1 + SS - 1) / SS;
    int xs = lo2 + (k * L2) / SS, xe = lo2 + ((k + 1) * L2 + SS - 1) / SS;
    const float* fb = f + (size_t)(b * CC + c) * VOL;
    float m = -INFINITY;
    for (int z = zs; z < ze; ++z)
        for (int y = ys; y < ye; ++y) {
            const float* row = fb + (z * DP + y) * DP;
            for (int x = xs; x < xe; ++x) m = fmaxf(m, row[x]);
        }
    out[tid] = m;
}

extern "C" void kernel_launch(void* const* d_in, const int* in_sizes, int n_in,
                              void* d_out, int out_size, void* d_ws, size_t ws_size,
                              hipStream_t stream) {
    const float* f     = (const float*)d_in[0];
    const float* props = (const float*)d_in[2];
    float* out = (float*)d_out;

    const int B = in_sizes[0] / (CC * VOL);   // 4
    const int N = in_sizes[2] / 8;            // 96

    const size_t ft_bytes = (size_t)B * VOL * CC * sizeof(__half);
    if (ws_size >= ft_bytes) {
        __half* ft = (__half*)d_ws;
        dim3 g1(VOL / 16, B);                 // 864 x 4 = 3456 blocks
        transpose_cl<<<g1, 256, 0, stream>>>(f, (uint4*)ft);
        dim3 g2(N, SS, 2);                    // 96 x 7 x 2 = 1344 blocks
        croproi_stream<<<g2, 256, 0, stream>>>(ft, props, out);
    } else {
        int total = N * CC * SS * SS * SS;
        croproi_fallback<<<(total + 255) / 256, 256, 0, stream>>>(f, props, out, total);
    }
}

// Round 20
// 17.199 us; speedup vs baseline: 1.0987x; 1.0987x over previous
//
#include <hip/hip_runtime.h>
#include <hip/hip_fp16.h>

// CropRoi: 3D adaptive max-pool over per-proposal crop boxes.
// f:        [B=4, C=64, 24, 24, 24] f32
// proposals:[N, 8] f32 = [b, score, cx, cy, cz, sx, sy, sz]
// out:      [N, C, 7, 7, 7] f32
//
// r19 = EXACT restore of r15, the measured champion (17.22 us):
// K1: 1728 blocks (32-spatial x 64-ch tile): 2 float4 loads + 1 uint4 store
//     per thread, plain (non-NT) memory ops.
// K2: streaming separable pool, j-split, grid (N,7,2) = 1344 blocks
//     (5.25 blocks/CU, 21 waves/CU): phase A contiguous zy-pool loads with
//     exact predication; phase B x-pool; phase C coalesced write-out.
//
// Experiment ledger (19 rounds): predication -3.1us (r8) and occupancy
// splits -1.3us (r15) are the only levers that paid. Null/negative: traffic
// cut (r16), NT hints (r18, +1.7), wave-halving (r11), block count (r7/r8),
// fusion (r6/r13), intra-dispatch cross-XCD sync (r9 grid.sync ~100us,
// r12 pc-flag ~155us — never again on MI355X). The two-dispatch pipeline
// is latency/ramp-governed at this problem size; 17.2us is its plateau.
// Precision: fp16 RTN on ~N(0,1); absmax 0.03125 << 0.099 threshold.

#define SS 7
#define CC 64
#define DP 24
#define DP2 (DP*DP)        // 576
#define VOL (DP*DP*DP)     // 13824
#define INV_SCALE 0.25f
#define NEGINF2 0xFC00FC00u

static __device__ __forceinline__ unsigned pkmax(unsigned a, unsigned b) {
    unsigned r;
    asm("v_pk_max_f16 %0, %1, %2" : "=v"(r) : "v"(a), "v"(b));
    return r;
}
static __device__ __forceinline__ uint4 pkmax4(uint4 a, uint4 b) {
    uint4 r;
    r.x = pkmax(a.x, b.x); r.y = pkmax(a.y, b.y);
    r.z = pkmax(a.z, b.z); r.w = pkmax(a.w, b.w);
    return r;
}

// ---------------- kernel 1: channel-last transpose to fp16 ----------------
// 32-spatial x 64-channel tile; 1728 blocks.
__global__ __launch_bounds__(256) void transpose_cl(
    const float* __restrict__ f,   // [B][CC][VOL] f32
    uint4* __restrict__ ft4)       // [B][VOL][CC/8]
{
    __shared__ float tile[64][33];     // 8448 B
    const int b  = blockIdx.y;
    const int s0 = blockIdx.x * 32;
    const int t  = threadIdx.x;
    const int x4 = (t & 7) * 4;        // spatial quad within tile
    const int rr = t >> 3;             // 0..31
    #pragma unroll
    for (int it = 0; it < 2; ++it) {
        const int r = it * 32 + rr;    // channel
        const float4 v = *(const float4*)&f[(size_t)(b * CC + r) * VOL + s0 + x4];
        tile[r][x4 + 0] = v.x; tile[r][x4 + 1] = v.y;
        tile[r][x4 + 2] = v.z; tile[r][x4 + 3] = v.w;
    }
    __syncthreads();
    const int s  = t >> 3;             // spatial within tile (0..31)
    const int c8 = (t & 7) * 8;        // channel octet
    __half h[8];
    #pragma unroll
    for (int u = 0; u < 8; ++u)
        h[u] = __float2half(tile[c8 + u][s]);   // 2-way bank alias: free
    ft4[((size_t)b * VOL + s0 + s) * (CC / 8) + (c8 >> 3)] = *(uint4*)h;
}

// ---------------- kernel 2: streaming separable pool, j-split ----------------
__global__ __launch_bounds__(256) void croproi_stream(
    const __half* __restrict__ ft,    // [B][VOL][CC] fp16
    const float* __restrict__ props,  // [N][8]
    float* __restrict__ out)          // [N][CC][343] f32
{
    __shared__ uint4 P[4 * 104];      // [j_local][x(13)][c8(8)]  6656 B
    __shared__ float obuf[28 * 68];   // 7616 B
    const int n  = blockIdx.x;
    const int i  = blockIdx.y;        // z-bin slice
    const int zc = blockIdx.z;        // j-half: 0 -> j 0..3, 1 -> j 4..6
    const int t  = threadIdx.x;

    // ---- box decode (wave-uniform -> SGPR) ----
    const float* p = props + (size_t)n * 8;
    int b = (int)p[0];
    int lo0, lo1, lo2, L0, L1, L2;
    {
        float c0f = p[2] - 0.5f * p[5];
        float c1f = c0f + p[5];
        int lo = (int)floorf(c0f * INV_SCALE); if (lo < 0) lo = 0;
        int hi = (int)ceilf (c1f * INV_SCALE); if (hi > DP) hi = DP;
        lo0 = lo; L0 = hi - lo;

        c0f = p[3] - 0.5f * p[6];
        c1f = c0f + p[6];
        lo = (int)floorf(c0f * INV_SCALE); if (lo < 0) lo = 0;
        hi = (int)ceilf (c1f * INV_SCALE); if (hi > DP) hi = DP;
        lo1 = lo; L1 = hi - lo;

        c0f = p[4] - 0.5f * p[7];
        c1f = c0f + p[7];
        lo = (int)floorf(c0f * INV_SCALE); if (lo < 0) lo = 0;
        hi = (int)ceilf (c1f * INV_SCALE); if (hi > DP) hi = DP;
        lo2 = lo; L2 = hi - lo;
    }
    b   = __builtin_amdgcn_readfirstlane(b);
    lo0 = __builtin_amdgcn_readfirstlane(lo0);
    lo1 = __builtin_amdgcn_readfirstlane(lo1);
    lo2 = __builtin_amdgcn_readfirstlane(lo2);
    L0  = __builtin_amdgcn_readfirstlane(L0);
    L1  = __builtin_amdgcn_readfirstlane(L1);
    L2  = __builtin_amdgcn_readfirstlane(L2);

    const int zs = (i * L0) / SS;
    const int ez = ((i + 1) * L0 + 6) / SS - zs;        // 1..3 (uniform)
    const int jlo = zc ? 4 : 0;
    const int nj  = zc ? 3 : 4;

    // base at (b, lo0+zs, lo1, lo2), channel 0, in uint4 units (8/point)
    const uint4* base0 = (const uint4*)ft
        + ((size_t)b * VOL + (size_t)(lo0 + zs) * DP2
           + (size_t)lo1 * DP + lo2) * 8;

    // ---- phase A: zy-pool streaming loads -> P[j_local][x][c8] ----
    // units: nj * 13x * 8c8 (<=416); lanes sweep c8 then x -> contiguous
    const int unitsA = nj * 104;
    for (int u = t; u < unitsA; u += 256) {
        const int jl = u / 104;                 // const-divisor magic
        const int r  = u - jl * 104;
        const int x  = r >> 3;
        const int c8 = r & 7;
        const int j  = jlo + jl;
        const int ys = (j * L1) / SS;
        const int ey = ((j + 1) * L1 + 6) / SS - ys;     // 1..3
        const bool act = (x < L2);

        const uint4* bp = base0 + (ys * DP + x) * 8 + c8;
        uint4 m; m.x = m.y = m.z = m.w = NEGINF2;
        #pragma unroll
        for (int zi = 0; zi < 3; ++zi) {
            if (zi < ez) {                      // wave-uniform branch
                const uint4* bz = bp + zi * (DP2 * 8);
                uint4 v0, v1, v2;
                v0.x = v0.y = v0.z = v0.w = NEGINF2; v1 = v0; v2 = v0;
                if (act)           v0 = bz[0];           // exec-masked
                if (act && ey > 1) v1 = bz[DP * 8];
                if (act && ey > 2) v2 = bz[2 * DP * 8];
                m = pkmax4(m, pkmax4(pkmax4(v0, v1), v2));
            }
        }
        if (act) P[jl * 104 + x * 8 + c8] = m;
    }
    __syncthreads();

    // ---- phase B: x-pool from P -> obuf f32 ----
    const int unitsB = nj * 56;                 // (nj*7 bins) * 8 c8
    if (t < unitsB) {
        const int jkl = t >> 3;                 // local bin (j_local*7 + k)
        const int c8  = t & 7;
        const int jl  = jkl / SS;               // const-divisor magic
        const int k   = jkl - jl * SS;
        const int xs  = (k * L2) / SS;
        const int ex  = ((k + 1) * L2 + 6) / SS - xs;    // 1..3
        const uint4* pp = &P[jl * 104 + xs * 8 + c8];
        uint4 m = pp[0];
        if (ex > 1) m = pkmax4(m, pp[8]);
        if (ex > 2) m = pkmax4(m, pp[16]);

        float* o = &obuf[jkl * 68 + c8 * 8];
        __half2 h;
        h = *(const __half2*)&m.x; o[0] = __half2float(h.x); o[1] = __half2float(h.y);
        h = *(const __half2*)&m.y; o[2] = __half2float(h.x); o[3] = __half2float(h.y);
        h = *(const __half2*)&m.z; o[4] = __half2float(h.x); o[5] = __half2float(h.y);
        h = *(const __half2*)&m.w; o[6] = __half2float(h.x); o[7] = __half2float(h.y);
    }
    __syncthreads();

    // ---- phase C: coalesced write-out (28/21-float runs per channel) ----
    float* op = out + (size_t)n * CC * (SS * SS * SS) + (size_t)i * 49 + jlo * SS;
    if (zc == 0) {
        for (int idx = t; idx < 28 * CC; idx += 256) {
            const int c = idx / 28;             // const-divisor magic
            const int q = idx - c * 28;
            op[(size_t)c * 343 + q] = obuf[q * 68 + c];
        }
    } else {
        for (int idx = t; idx < 21 * CC; idx += 256) {
            const int c = idx / 21;             // const-divisor magic
            const int q = idx - c * 21;
            op[(size_t)c * 343 + q] = obuf[q * 68 + c];
        }
    }
}

// ---------------- fallback: round-0 thread-per-bin (proven) --------
__global__ __launch_bounds__(256) void croproi_fallback(
    const float* __restrict__ f, const float* __restrict__ props,
    float* __restrict__ out, int total)
{
    int tid = blockIdx.x * blockDim.x + threadIdx.x;
    if (tid >= total) return;
    int k = tid % SS;
    int t = tid / SS;
    int j = t % SS; t /= SS;
    int i = t % SS; t /= SS;
    int c = t % CC;
    int n = t / CC;
    const float* p = props + n * 8;
    int b = (int)p[0];
    int lo0, lo1, lo2, L0, L1, L2;
    {
        float c0f = p[2] - 0.5f * p[5]; float c1f = c0f + p[5];
        int lo = (int)floorf(c0f * INV_SCALE); if (lo < 0) lo = 0;
        int hi = (int)ceilf (c1f * INV_SCALE); if (hi > DP) hi = DP;
        lo0 = lo; L0 = hi - lo;
        c0f = p[3] - 0.5f * p[6]; c1f = c0f + p[6];
        lo = (int)floorf(c0f * INV_SCALE); if (lo < 0) lo = 0;
        hi = (int)ceilf (c1f * INV_SCALE); if (hi > DP) hi = DP;
        lo1 = lo; L1 = hi - lo;
        c0f = p[4] - 0.5f * p[7]; c1f = c0f + p[7];
        lo = (int)floorf(c0f * INV_SCALE); if (lo < 0) lo = 0;
        hi = (int)ceilf (c1f * INV_SCALE); if (hi > DP) hi = DP;
        lo2 = lo; L2 = hi - lo;
    }
    int zs = lo0 + (i * L0) / SS, ze = lo0 + ((i + 1) * L0 + SS - 1) / SS;
    int ys = lo1 + (j * L1) / SS, ye = lo1 + ((j + 1) * L1 + SS - 1) / SS;
    int xs = lo2 + (k * L2) / SS, xe = lo2 + ((k + 1) * L2 + SS - 1) / SS;
    const float* fb = f + (size_t)(b * CC + c) * VOL;
    float m = -INFINITY;
    for (int z = zs; z < ze; ++z)
        for (int y = ys; y < ye; ++y) {
            const float* row = fb + (z * DP + y) * DP;
            for (int x = xs; x < xe; ++x) m = fmaxf(m, row[x]);
        }
    out[tid] = m;
}

extern "C" void kernel_launch(void* const* d_in, const int* in_sizes, int n_in,
                              void* d_out, int out_size, void* d_ws, size_t ws_size,
                              hipStream_t stream) {
    const float* f     = (const float*)d_in[0];
    const float* props = (const float*)d_in[2];
    float* out = (float*)d_out;

    const int B = in_sizes[0] / (CC * VOL);   // 4
    const int N = in_sizes[2] / 8;            // 96

    const size_t ft_bytes = (size_t)B * VOL * CC * sizeof(__half);
    if (ws_size >= ft_bytes) {
        __half* ft = (__half*)d_ws;
        dim3 g1(VOL / 32, B);                 // 432 x 4 = 1728 blocks
        transpose_cl<<<g1, 256, 0, stream>>>(f, (uint4*)ft);
        dim3 g2(N, SS, 2);                    // 96 x 7 x 2 = 1344 blocks
        croproi_stream<<<g2, 256, 0, stream>>>(ft, props, out);
    } else {
        int total = N * CC * SS * SS * SS;
        croproi_fallback<<<(total + 255) / 256, 256, 0, stream>>>(f, props, out, total);
    }
}